// Round 7
// baseline (54.248 us; speedup 1.0000x reference)
//
#include <hip/hip_runtime.h>
#include <cstddef>

#define PMOD 97
#define HID 512
#define NPAIR 9409
#define NSTEPS 15
#define CAP 96

typedef __attribute__((ext_vector_type(8))) short short8;
typedef __attribute__((ext_vector_type(4))) short short4_t;
typedef __attribute__((ext_vector_type(4))) float f32x4;

static __device__ __forceinline__ unsigned short f2bf_rn(float f) {
    unsigned u = __float_as_uint(f);
    u += 0x7FFFu + ((u >> 16) & 1u);
    return (unsigned short)(u >> 16);
}
static __device__ __forceinline__ float bf2f(unsigned short h) {
    return __uint_as_float(((unsigned)h) << 16);
}
static __device__ __forceinline__ void split_hilo(const float* __restrict__ p,
                                                  short8& hi, short8& lo) {
    const float4 v0 = *(const float4*)p;
    const float4 v1 = *(const float4*)(p + 4);
    const float vv[8] = {v0.x, v0.y, v0.z, v0.w, v1.x, v1.y, v1.z, v1.w};
#pragma unroll
    for (int q = 0; q < 8; ++q) {
        const unsigned short hb = f2bf_rn(vv[q]);
        hi[q] = (short)hb;
        lo[q] = (short)f2bf_rn(vv[q] - bf2f(hb));
    }
}

// ---------------------------------------------------------------------------
// k_abm: fused (a) W2->bf16 convert, (b) inverse-index build pid->{b},
//        (c) MFMA GEMM for cur1 parts (Ap with b1, Bm), hi/lo 3-pass bf16.
// Grid = 7 mt x 64 ng = 448 blocks; 4 waves = 4 k-quarters, LDS reduce.
// cnt[] must be zeroed by a preceding memset node.
// ---------------------------------------------------------------------------
__global__ __launch_bounds__(256) void k_abm(const float* __restrict__ embed,
                                             const float* __restrict__ W1,
                                             const float* __restrict__ W2,
                                             const float* __restrict__ b1,
                                             const int* __restrict__ x,
                                             int nB,
                                             short* __restrict__ w2bf,
                                             int* __restrict__ cnt,
                                             int* __restrict__ blist,
                                             float* __restrict__ Ap,
                                             float* __restrict__ Bm) {
    __shared__ f32x4 red[3][64];   // 3 KB

    const int t = threadIdx.x;
    const int lane = t & 63;
    const int kq = t >> 6;
    const int gid = blockIdx.x * 256 + t;

    // ---- (a) W2 convert: blocks 0..48 ----
    if (gid < PMOD * HID / 4) {
        const float4 v = ((const float4*)W2)[gid];
        const float vv[4] = {v.x, v.y, v.z, v.w};
        short4_t h4;
#pragma unroll
        for (int q = 0; q < 4; ++q) h4[q] = (short)f2bf_rn(vv[q]);
        *(short4_t*)(w2bf + gid * 4) = h4;
    }

    // ---- (b) inverse index: blocks 0..127 ----
    if (gid < nB) {
        const int x0 = x[2 * gid];
        const int x1 = x[2 * gid + 1];
        const int pid = x0 * PMOD + x1;
        const int slot = atomicAdd(&cnt[pid], 1);
        if (slot < CAP) blist[pid * CAP + slot] = gid;
    }

    // ---- (c) GEMM ----
    const int mt = blockIdx.x >> 6;      // 0..6
    const int ng = blockIdx.x & 63;      // 0..63
    int e = mt * 16 + (lane & 15);
    if (e > PMOD - 1) e = PMOD - 1;
    const int n = ng * 16 + (lane & 15); // 0..1023
    const int h = n & 511;
    const int half = n >> 9;
    const int kbase = kq * 128 + (lane >> 4) * 8;

    f32x4 acc = (f32x4){0.f, 0.f, 0.f, 0.f};
#pragma unroll
    for (int kt = 0; kt < 4; ++kt) {
        const int k = kbase + kt * 32;
        short8 ahi, alo, bhi, blo;
        split_hilo(embed + (size_t)e * HID + k, ahi, alo);
        split_hilo(W1 + (size_t)h * 1024 + half * HID + k, bhi, blo);
        acc = __builtin_amdgcn_mfma_f32_16x16x32_bf16(ahi, bhi, acc, 0, 0, 0);
        acc = __builtin_amdgcn_mfma_f32_16x16x32_bf16(alo, bhi, acc, 0, 0, 0);
        acc = __builtin_amdgcn_mfma_f32_16x16x32_bf16(ahi, blo, acc, 0, 0, 0);
    }

    if (kq != 0) red[kq - 1][lane] = acc;
    __syncthreads();
    if (kq == 0) {
        acc += red[0][lane];
        acc += red[1][lane];
        acc += red[2][lane];
        const float bias = half ? 0.f : b1[h];
#pragma unroll
        for (int reg = 0; reg < 4; ++reg) {
            const int er = mt * 16 + (lane >> 4) * 4 + reg;
            if (er < PMOD) {
                if (half == 0) Ap[(size_t)er * HID + h] = acc[reg] + bias;
                else           Bm[(size_t)er * HID + h] = acc[reg];
            }
        }
    }
}

// ---------------------------------------------------------------------------
// k_pairs v5: 589 blocks x 8 waves (512 thr), direct scatter to out.
//   sim phase: wave w sims k-tiles {2w,2w+1} in registers; bf16 A-frags
//   published to LDS wfrag[kt][lane].
//   GEMM phase: wave = (kq=w&3, nh=w>>2); LDS reduce over kq.
//   epilogue (kq==0): for each pair row prow, loop its b-list and write
//   out[b][o] directly (64B contiguous per 16-lane group).
// ---------------------------------------------------------------------------
__global__ __launch_bounds__(512) void k_pairs(const float* __restrict__ Ap,
                                               const float* __restrict__ Bm,
                                               const short* __restrict__ w2bf,
                                               const float* __restrict__ b2,
                                               const float* __restrict__ pbeta1,
                                               const float* __restrict__ pbeta2,
                                               const float* __restrict__ pthr1,
                                               const int* __restrict__ cnt,
                                               const int* __restrict__ blist,
                                               float* __restrict__ out) {
    __shared__ short8 wfrag[16][64];      // 16 KB
    __shared__ f32x4 red[2][3][4][64];    // 24 KB

    const float beta1 = fminf(fmaxf(pbeta1[0], 0.1f), 0.9f);
    const float beta2 = fminf(fmaxf(pbeta2[0], 0.1f), 0.9f);
    const float thr   = fmaxf(pthr1[0], 0.1f);

    const int t = threadIdx.x;
    const int lane = t & 63;
    const int w = t >> 6;                 // 0..7
    const int pblk = blockIdx.x * 16;

    const int pid0 = pblk + (lane & 15);
    const int pid  = (pid0 < NPAIR) ? pid0 : (NPAIR - 1);
    const unsigned i = (unsigned)pid / PMOD;
    const unsigned j = (unsigned)pid - i * PMOD;

    // ---- sim phase ----
#pragma unroll
    for (int kk = 0; kk < 2; ++kk) {
        const int kt = 2 * w + kk;
        const int h = kt * 32 + (lane >> 4) * 8;
        const float* ap = Ap + (size_t)i * HID + h;
        const float* bp = Bm + (size_t)j * HID + h;
        const float4 a0 = *(const float4*)ap;
        const float4 a1 = *(const float4*)(ap + 4);
        const float4 g0 = *(const float4*)bp;
        const float4 g1 = *(const float4*)(bp + 4);
        float c[8] = {a0.x + g0.x, a0.y + g0.y, a0.z + g0.z, a0.w + g0.w,
                      a1.x + g1.x, a1.y + g1.y, a1.z + g1.z, a1.w + g1.w};
        float cm[8], m[8], wv[8];
        bool sb[8];
#pragma unroll
        for (int q = 0; q < 8; ++q) {
            cm[q] = c[q] - thr; m[q] = 0.f; wv[q] = 0.f; sb[q] = false;
        }
        for (int s = 0; s < NSTEPS; ++s) {
#pragma unroll
            for (int q = 0; q < 8; ++q) {
                const float cadj = sb[q] ? cm[q] : c[q];
                m[q] = fmaf(beta1, m[q], cadj);
                sb[q] = m[q] > thr;
                wv[q] = fmaf(beta2, wv[q], sb[q] ? 1.f : 0.f);
            }
        }
        short8 af;
#pragma unroll
        for (int q = 0; q < 8; ++q) af[q] = (short)f2bf_rn(wv[q]);
        wfrag[kt][lane] = af;
    }
    __syncthreads();

    // ---- GEMM phase ----
    const int kq = w & 3;
    const int nh = w >> 2;
    const int ntb = nh * 4;               // 0 or 4

    f32x4 acc[4];
#pragma unroll
    for (int q = 0; q < 4; ++q) acc[q] = (f32x4){0.f, 0.f, 0.f, 0.f};

#pragma unroll
    for (int kk = 0; kk < 4; ++kk) {
        const int kt = kq * 4 + kk;
        const short8 af = wfrag[kt][lane];
        const int k = kt * 32 + (lane >> 4) * 8;
#pragma unroll
        for (int q = 0; q < 4; ++q) {
            const int nt = ntb + q;
            if (nt < 7) {
                const int o0 = nt * 16 + (lane & 15);
                const int oc = (o0 < PMOD) ? o0 : (PMOD - 1);
                const short8 bf = *(const short8*)(w2bf + (size_t)oc * HID + k);
                acc[q] = __builtin_amdgcn_mfma_f32_16x16x32_bf16(af, bf, acc[q], 0, 0, 0);
            }
        }
    }

    if (kq != 0) {
#pragma unroll
        for (int q = 0; q < 4; ++q)
            if (ntb + q < 7) red[nh][kq - 1][q][lane] = acc[q];
    }
    __syncthreads();
    if (kq == 0) {
        float S = 0.f;
#pragma unroll
        for (int s = 0; s < NSTEPS; ++s) S = fmaf(beta2, S, 1.f);

        // finalize values + per-o bias
        float biasq[4];
#pragma unroll
        for (int q = 0; q < 4; ++q) {
            const int nt = ntb + q;
            if (nt < 7) {
                acc[q] += red[nh][0][q][lane];
                acc[q] += red[nh][1][q][lane];
                acc[q] += red[nh][2][q][lane];
                const int o = nt * 16 + (lane & 15);
                biasq[q] = (o < PMOD) ? b2[o] * S : 0.f;
            } else biasq[q] = 0.f;
        }

        // direct scatter: each prow -> its b-list
#pragma unroll
        for (int reg = 0; reg < 4; ++reg) {
            const int prow = pblk + (lane >> 4) * 4 + reg;
            const int nb = (prow < NPAIR) ? cnt[prow] : 0;
            for (int s = 0; s < nb; ++s) {
                const int b = blist[prow * CAP + s];
                float* orow = out + (size_t)b * PMOD;
#pragma unroll
                for (int q = 0; q < 4; ++q) {
                    const int nt = ntb + q;
                    if (nt < 7) {
                        const int o = nt * 16 + (lane & 15);
                        if (o < PMOD) orow[o] = acc[q][reg] + biasq[q];
                    }
                }
            }
        }
    }
}

// ---------------------------------------------------------------------------
extern "C" void kernel_launch(void* const* d_in, const int* in_sizes, int n_in,
                              void* d_out, int out_size, void* d_ws, size_t ws_size,
                              hipStream_t stream) {
    const int*   x     = (const int*)d_in[0];
    const float* embed = (const float*)d_in[1];
    const float* W1    = (const float*)d_in[2];
    const float* b1    = (const float*)d_in[3];
    const float* W2    = (const float*)d_in[4];
    const float* b2    = (const float*)d_in[5];
    const float* beta1 = (const float*)d_in[6];
    const float* beta2 = (const float*)d_in[7];
    const float* thr1  = (const float*)d_in[8];

    float* out = (float*)d_out;
    const int B = in_sizes[0] / 2;

    // ws layout (4,150,656 B total):
    //   0:         cnt    (9409*4 = 37,636; padded to 40,960)
    //   40,960:    blist  (9409*96*4 = 3,613,056)
    //   3,654,016: w2bf   (97*512*2 = 99,328)
    //   3,753,344: Ap     (97*512*4 = 198,656)
    //   3,952,000: Bm     (97*512*4 = 198,656)
    char* ws = (char*)d_ws;
    int*   cnt   = (int*)(ws);
    int*   blist = (int*)(ws + 40960);
    short* w2bf  = (short*)(ws + 3654016);
    float* Ap    = (float*)(ws + 3753344);
    float* Bm    = (float*)(ws + 3952000);

    hipMemsetAsync(cnt, 0, NPAIR * sizeof(int), stream);

    k_abm<<<448, 256, 0, stream>>>(embed, W1, W2, b1, x, B, w2bf, cnt, blist, Ap, Bm);

    const int nblk = (NPAIR + 15) / 16;   // 589 blocks x 8 waves
    k_pairs<<<nblk, 512, 0, stream>>>(Ap, Bm, w2bf, b2, beta1, beta2, thr1,
                                      cnt, blist, out);
}

// Round 8
// 41.068 us; speedup vs baseline: 1.3209x; 1.3209x over previous
//
#include <hip/hip_runtime.h>
#include <cstddef>

#define PMOD 97
#define HID 512
#define NPAIR 9409
#define NSTEPS 15

typedef __attribute__((ext_vector_type(8))) short short8;
typedef __attribute__((ext_vector_type(4))) short short4_t;
typedef __attribute__((ext_vector_type(4))) float f32x4;

static __device__ __forceinline__ unsigned short f2bf_rn(float f) {
    unsigned u = __float_as_uint(f);
    u += 0x7FFFu + ((u >> 16) & 1u);
    return (unsigned short)(u >> 16);
}
static __device__ __forceinline__ float bf2f(unsigned short h) {
    return __uint_as_float(((unsigned)h) << 16);
}
static __device__ __forceinline__ void split_hilo(const float* __restrict__ p,
                                                  short8& hi, short8& lo) {
    const float4 v0 = *(const float4*)p;
    const float4 v1 = *(const float4*)(p + 4);
    const float vv[8] = {v0.x, v0.y, v0.z, v0.w, v1.x, v1.y, v1.z, v1.w};
#pragma unroll
    for (int q = 0; q < 8; ++q) {
        const unsigned short hb = f2bf_rn(vv[q]);
        hi[q] = (short)hb;
        lo[q] = (short)f2bf_rn(vv[q] - bf2f(hb));
    }
}

// ---------------------------------------------------------------------------
// k_abm: fused W2->bf16 convert + MFMA GEMM for cur1 parts (Ap w/ b1, Bm).
// Unchanged from R6 (numerics-preserving). Grid = 7 mt x 64 ng = 448 blocks;
// 4 waves = 4 k-quarters, LDS reduce.
// ---------------------------------------------------------------------------
__global__ __launch_bounds__(256) void k_abm(const float* __restrict__ embed,
                                             const float* __restrict__ W1,
                                             const float* __restrict__ W2,
                                             const float* __restrict__ b1,
                                             short* __restrict__ w2bf,
                                             float* __restrict__ Ap,
                                             float* __restrict__ Bm) {
    __shared__ f32x4 red[3][64];   // 3 KB

    const int t = threadIdx.x;
    const int lane = t & 63;
    const int kq = t >> 6;

    // ---- W2 convert: blocks 0..48 ----
    const int gid = blockIdx.x * 256 + t;
    if (gid < PMOD * HID / 4) {
        const float4 v = ((const float4*)W2)[gid];
        const float vv[4] = {v.x, v.y, v.z, v.w};
        short4_t h4;
#pragma unroll
        for (int q = 0; q < 4; ++q) h4[q] = (short)f2bf_rn(vv[q]);
        *(short4_t*)(w2bf + gid * 4) = h4;
    }

    // ---- GEMM ----
    const int mt = blockIdx.x >> 6;      // 0..6
    const int ng = blockIdx.x & 63;      // 0..63
    int e = mt * 16 + (lane & 15);
    if (e > PMOD - 1) e = PMOD - 1;
    const int n = ng * 16 + (lane & 15); // 0..1023
    const int h = n & 511;
    const int half = n >> 9;
    const int kbase = kq * 128 + (lane >> 4) * 8;

    f32x4 acc = (f32x4){0.f, 0.f, 0.f, 0.f};
#pragma unroll
    for (int kt = 0; kt < 4; ++kt) {
        const int k = kbase + kt * 32;
        short8 ahi, alo, bhi, blo;
        split_hilo(embed + (size_t)e * HID + k, ahi, alo);
        split_hilo(W1 + (size_t)h * 1024 + half * HID + k, bhi, blo);
        acc = __builtin_amdgcn_mfma_f32_16x16x32_bf16(ahi, bhi, acc, 0, 0, 0);
        acc = __builtin_amdgcn_mfma_f32_16x16x32_bf16(alo, bhi, acc, 0, 0, 0);
        acc = __builtin_amdgcn_mfma_f32_16x16x32_bf16(ahi, blo, acc, 0, 0, 0);
    }

    if (kq != 0) red[kq - 1][lane] = acc;
    __syncthreads();
    if (kq == 0) {
        acc += red[0][lane];
        acc += red[1][lane];
        acc += red[2][lane];
        const float bias = half ? 0.f : b1[h];
#pragma unroll
        for (int reg = 0; reg < 4; ++reg) {
            const int er = mt * 16 + (lane >> 4) * 4 + reg;
            if (er < PMOD) {
                if (half == 0) Ap[(size_t)er * HID + h] = acc[reg] + bias;
                else           Bm[(size_t)er * HID + h] = acc[reg];
            }
        }
    }
}

// ---------------------------------------------------------------------------
// k_pairs v6: 589 blocks x 16 waves (1024 thr). Max-TLP restructure:
//   sim phase: wave w sims exactly ONE k-tile kt=w (half the serial chain
//   of v5); lane owns pair m=lane&15, k-chunk (lane>>4)*8; 15 LIF steps in
//   registers; bf16 A-frag -> wfrag[kt][lane].
//   GEMM phase: wave = (kq=w&3, ns=w>>2); kq covers 4 k-tiles, ns covers
//   n-tiles {2ns, 2ns+1} (7 total). LDS reduce over kq (order identical to
//   v5 -> bitwise-same pairOut); kq==0 stores pairOut + b2*S.
// ---------------------------------------------------------------------------
__global__ __launch_bounds__(1024) void k_pairs(const float* __restrict__ Ap,
                                                const float* __restrict__ Bm,
                                                const short* __restrict__ w2bf,
                                                const float* __restrict__ b2,
                                                const float* __restrict__ pbeta1,
                                                const float* __restrict__ pbeta2,
                                                const float* __restrict__ pthr1,
                                                float* __restrict__ pairOut) {
    __shared__ short8 wfrag[16][64];   // 16 KB
    __shared__ f32x4 red[3][7][64];    // 21.5 KB

    const float beta1 = fminf(fmaxf(pbeta1[0], 0.1f), 0.9f);
    const float beta2 = fminf(fmaxf(pbeta2[0], 0.1f), 0.9f);
    const float thr   = fmaxf(pthr1[0], 0.1f);

    const int t = threadIdx.x;
    const int lane = t & 63;
    const int w = t >> 6;              // 0..15
    const int pblk = blockIdx.x * 16;

    const int pid0 = pblk + (lane & 15);
    const int pid  = (pid0 < NPAIR) ? pid0 : (NPAIR - 1);
    const unsigned i = (unsigned)pid / PMOD;
    const unsigned j = (unsigned)pid - i * PMOD;

    // ---- sim phase: one k-tile per wave ----
    {
        const int kt = w;
        const int h = kt * 32 + (lane >> 4) * 8;
        const float* ap = Ap + (size_t)i * HID + h;
        const float* bp = Bm + (size_t)j * HID + h;
        const float4 a0 = *(const float4*)ap;
        const float4 a1 = *(const float4*)(ap + 4);
        const float4 g0 = *(const float4*)bp;
        const float4 g1 = *(const float4*)(bp + 4);
        float c[8] = {a0.x + g0.x, a0.y + g0.y, a0.z + g0.z, a0.w + g0.w,
                      a1.x + g1.x, a1.y + g1.y, a1.z + g1.z, a1.w + g1.w};
        float cm[8], m[8], wv[8];
        bool sb[8];
#pragma unroll
        for (int q = 0; q < 8; ++q) {
            cm[q] = c[q] - thr; m[q] = 0.f; wv[q] = 0.f; sb[q] = false;
        }
        for (int s = 0; s < NSTEPS; ++s) {
#pragma unroll
            for (int q = 0; q < 8; ++q) {
                const float cadj = sb[q] ? cm[q] : c[q];
                m[q] = fmaf(beta1, m[q], cadj);
                sb[q] = m[q] > thr;
                wv[q] = fmaf(beta2, wv[q], sb[q] ? 1.f : 0.f);
            }
        }
        short8 af;
#pragma unroll
        for (int q = 0; q < 8; ++q) af[q] = (short)f2bf_rn(wv[q]);
        wfrag[kt][lane] = af;
    }
    __syncthreads();

    // ---- GEMM phase ----
    const int kq = w & 3;
    const int ns = w >> 2;             // 0..3
    f32x4 acc[2];
#pragma unroll
    for (int q = 0; q < 2; ++q) acc[q] = (f32x4){0.f, 0.f, 0.f, 0.f};

#pragma unroll
    for (int kk = 0; kk < 4; ++kk) {
        const int kt = kq * 4 + kk;
        const short8 af = wfrag[kt][lane];
        const int k = kt * 32 + (lane >> 4) * 8;
#pragma unroll
        for (int q = 0; q < 2; ++q) {
            const int nt = ns * 2 + q;
            if (nt < 7) {
                const int o0 = nt * 16 + (lane & 15);
                const int oc = (o0 < PMOD) ? o0 : (PMOD - 1);
                const short8 bf = *(const short8*)(w2bf + (size_t)oc * HID + k);
                acc[q] = __builtin_amdgcn_mfma_f32_16x16x32_bf16(af, bf, acc[q], 0, 0, 0);
            }
        }
    }

    if (kq != 0) {
#pragma unroll
        for (int q = 0; q < 2; ++q) {
            const int nt = ns * 2 + q;
            if (nt < 7) red[kq - 1][nt][lane] = acc[q];
        }
    }
    __syncthreads();
    if (kq == 0) {
        float S = 0.f;
#pragma unroll
        for (int s = 0; s < NSTEPS; ++s) S = fmaf(beta2, S, 1.f);
#pragma unroll
        for (int q = 0; q < 2; ++q) {
            const int nt = ns * 2 + q;
            if (nt < 7) {
                f32x4 a = acc[q];
                a += red[0][nt][lane];
                a += red[1][nt][lane];
                a += red[2][nt][lane];
                const int o = nt * 16 + (lane & 15);
                if (o < PMOD) {
                    const float bias = b2[o] * S;
#pragma unroll
                    for (int reg = 0; reg < 4; ++reg) {
                        const int prow = pblk + (lane >> 4) * 4 + reg;
                        if (prow < NPAIR)
                            pairOut[(size_t)prow * PMOD + o] = a[reg] + bias;
                    }
                }
            }
        }
    }
}

// ---------------------------------------------------------------------------
// k_scatter: out[b][o] = pairOut[x[b,0]*97 + x[b,1]][o]  (coalesced)
// ---------------------------------------------------------------------------
__global__ __launch_bounds__(256) void k_scatter(const int* __restrict__ x,
                                                 const float* __restrict__ pairOut,
                                                 float* __restrict__ out,
                                                 int total) {
    const unsigned idx = blockIdx.x * 256u + threadIdx.x;
    if (idx >= (unsigned)total) return;
    const unsigned b = idx / PMOD;
    const unsigned o = idx - b * PMOD;
    const int pid = x[2 * b] * PMOD + x[2 * b + 1];
    out[idx] = pairOut[(size_t)pid * PMOD + o];
}

// ---------------------------------------------------------------------------
extern "C" void kernel_launch(void* const* d_in, const int* in_sizes, int n_in,
                              void* d_out, int out_size, void* d_ws, size_t ws_size,
                              hipStream_t stream) {
    const int*   x     = (const int*)d_in[0];
    const float* embed = (const float*)d_in[1];
    const float* W1    = (const float*)d_in[2];
    const float* b1    = (const float*)d_in[3];
    const float* W2    = (const float*)d_in[4];
    const float* b2    = (const float*)d_in[5];
    const float* beta1 = (const float*)d_in[6];
    const float* beta2 = (const float*)d_in[7];
    const float* thr1  = (const float*)d_in[8];

    float* out = (float*)d_out;
    const int B = in_sizes[0] / 2;

    // ws layout (4,147,456 B):
    //   0:         pairOut (9409*97*4 = 3,650,816)
    //   3,650,816: w2bf    (97*512*2 =    99,328)
    //   3,750,144: Ap      (97*512*4 =   198,656)
    //   3,948,800: Bm      (97*512*4 =   198,656)
    char* ws = (char*)d_ws;
    float* pairOut = (float*)(ws);
    short* w2bf    = (short*)(ws + 3650816);
    float* Ap      = (float*)(ws + 3750144);
    float* Bm      = (float*)(ws + 3948800);

    k_abm<<<448, 256, 0, stream>>>(embed, W1, W2, b1, w2bf, Ap, Bm);

    const int nblk = (NPAIR + 15) / 16;   // 589 blocks x 16 waves
    k_pairs<<<nblk, 1024, 0, stream>>>(Ap, Bm, w2bf, b2, beta1, beta2, thr1, pairOut);

    const int total = B * PMOD;
    k_scatter<<<(total + 255) / 256, 256, 0, stream>>>(x, pairOut, out, total);
}